// Round 1
// baseline (741.764 us; speedup 1.0000x reference)
//
#include <hip/hip_runtime.h>
#include <math.h>

#define BB 32
#define CC 3
#define HH 224
#define WW 224
#define HWS (HH*WW)            // 50176
#define NPIX (BB*HWS)          // 1,605,632 pixels
#define NTAPS (9*HWS)          // 451,584
#define EPS_IN 1e-5f
#define LNUM 10

#define NBLK (NPIX/256)        // 6272 blocks, thread = one (b,h,w) pixel

__device__ __forceinline__ float fast_tanh(float z) {
    z = fminf(fmaxf(z, -15.f), 15.f);
    float e = __expf(2.f * z);
    return (e - 1.f) * __frcp_rn(e + 1.f);
}

// ---------------- zero stats ----------------
__global__ void zero_kernel(float* __restrict__ p, int n) {
    int i = blockIdx.x * 256 + threadIdx.x;
    if (i < n) p[i] = 0.f;
}

// ------- precompute expanded taps: clamped BYTE offsets (idx*16 for the
// float4-interleaved activation layout) + masked bilinear weights ------
__global__ __launch_bounds__(256) void taps_kernel(
    const float* __restrict__ off,   // [18,H,W] batch-0 offset plane
    int4* __restrict__ ti, float4* __restrict__ tw)
{
    int gid = blockIdx.x * 256 + threadIdx.x;    // k*HWS + pix, grid exact
    int k = gid / HWS, pix = gid - k * HWS;
    int h = pix / WW, wc = pix - h * WW;
    int ky = k / 3, kx = k - 3 * ky;
    float dy = off[(2 * k)     * HWS + pix];
    float dx = off[(2 * k + 1) * HWS + pix];
    float py = (float)(h  + ky - 1) + dy;
    float px = (float)(wc + kx - 1) + dx;
    float y0f = floorf(py), x0f = floorf(px);
    float wy = py - y0f, wx = px - x0f;
    int iy0 = (int)y0f, ix0 = (int)x0f;
    int iy1 = iy0 + 1,  ix1 = ix0 + 1;
    float vy0 = (iy0 >= 0 && iy0 < HH) ? 1.f : 0.f;
    float vy1 = (iy1 >= 0 && iy1 < HH) ? 1.f : 0.f;
    float vx0 = (ix0 >= 0 && ix0 < WW) ? 1.f : 0.f;
    float vx1 = (ix1 >= 0 && ix1 < WW) ? 1.f : 0.f;
    int cy0 = min(max(iy0, 0), HH - 1), cy1 = min(max(iy1, 0), HH - 1);
    int cx0 = min(max(ix0, 0), WW - 1), cx1 = min(max(ix1, 0), WW - 1);
    int4 ii;
    ii.x = (cy0 * WW + cx0) << 4;    // byte offsets into float4-interleaved plane
    ii.y = (cy0 * WW + cx1) << 4;
    ii.z = (cy1 * WW + cx0) << 4;
    ii.w = (cy1 * WW + cx1) << 4;
    float4 ww;
    ww.x = (1.f - wy) * (1.f - wx) * vy0 * vx0;
    ww.y = (1.f - wy) * wx         * vy0 * vx1;
    ww.z = wy         * (1.f - wx) * vy1 * vx0;
    ww.w = wy         * wx         * vy1 * vx1;
    ti[gid] = ii; tw[gid] = ww;
}

// ------- pack planar x [B,3,H,W] -> interleaved [B,H,W,4] (once) -------
__global__ __launch_bounds__(256) void pack_kernel(
    const float* __restrict__ x, float4* __restrict__ xi)
{
    int g = blockIdx.x * 256 + threadIdx.x;      // grid exact: NPIX
    int b = g / HWS, pix = g - b * HWS;
    const float* xb = x + (size_t)b * (CC * HWS) + pix;
    xi[g] = make_float4(xb[0], xb[HWS], xb[2 * HWS], 0.f);
}

// ---------------- deformable conv (+stats), interleaved layout ----------------
// One thread = one (b,h,w) pixel, all 3 out channels. KEY CHANGE vs planar:
// the 4 bilinear-corner indices are shared across input channels, so in the
// [B,H,W,4] layout each corner is ONE float4 gather (3 channels at once):
// 108 scalar gathers -> 36 dwordx4 gathers, 3 stores -> 1. Conv was bound by
// vector-mem instruction issue (TA address processing), not bytes, so this
// cuts its critical resource ~2.3x. Only the int4 indices are hoisted (36
// VGPR); tw + gathers stream through the loop so the 128-VGPR cap (256,4)
// holds without spills. XCD-contiguous block swizzle kept for L2 locality.
__global__ __launch_bounds__(256, 4) void conv_kernel(
    const float4* __restrict__ xi,   // [B*HWS] interleaved
    const int4*  __restrict__ ti,    // [9,HW] corner byte offsets
    const float4* __restrict__ tw,   // [9,HW] bilinear weights
    const float* __restrict__ wt,    // [3,3,9]
    float4* __restrict__ y,          // [B*HWS] interleaved
    float* __restrict__ stats)       // [B*3][2]
{
    __shared__ float w_s[81];
    int t = threadIdx.x;
    if (t < 81) w_s[t] = wt[t];
    __syncthreads();

    int p = blockIdx.x;
    int logical = (p & 7) * (NBLK / 8) + (p >> 3);
    int b     = logical & 31;
    int chunk = logical >> 5;            // 0..195
    int pix   = chunk * 256 + t;

    const char* xb = (const char*)(xi + (size_t)b * HWS);

    int4 ii[9];
    #pragma unroll
    for (int k = 0; k < 9; ++k) ii[k] = ti[k * HWS + pix];

    float acc0 = 0.f, acc1 = 0.f, acc2 = 0.f;

    #pragma unroll
    for (int k = 0; k < 9; ++k) {
        float4 w   = tw[k * HWS + pix];
        float4 v00 = *(const float4*)(xb + ii[k].x);
        float4 v01 = *(const float4*)(xb + ii[k].y);
        float4 v10 = *(const float4*)(xb + ii[k].z);
        float4 v11 = *(const float4*)(xb + ii[k].w);
        float s0 = v00.x * w.x + v01.x * w.y + v10.x * w.z + v11.x * w.w;
        float s1 = v00.y * w.x + v01.y * w.y + v10.y * w.z + v11.y * w.w;
        float s2 = v00.z * w.x + v01.z * w.y + v10.z * w.z + v11.z * w.w;
        acc0 = fmaf(s2, w_s[18 + k], fmaf(s1, w_s[ 9 + k], fmaf(s0, w_s[     k], acc0)));
        acc1 = fmaf(s2, w_s[45 + k], fmaf(s1, w_s[36 + k], fmaf(s0, w_s[27 + k], acc1)));
        acc2 = fmaf(s2, w_s[72 + k], fmaf(s1, w_s[63 + k], fmaf(s0, w_s[54 + k], acc2)));
    }

    y[(size_t)b * HWS + pix] = make_float4(acc0, acc1, acc2, 0.f);

    // ---- per-(b,channel) sum / sumsq reduction ----
    float s0r = acc0, q0 = acc0 * acc0;
    float s1r = acc1, q1 = acc1 * acc1;
    float s2r = acc2, q2 = acc2 * acc2;
    #pragma unroll
    for (int o = 32; o > 0; o >>= 1) {
        s0r += __shfl_down(s0r, o); q0 += __shfl_down(q0, o);
        s1r += __shfl_down(s1r, o); q1 += __shfl_down(q1, o);
        s2r += __shfl_down(s2r, o); q2 += __shfl_down(q2, o);
    }
    __shared__ float red[4][6];
    int wave = t >> 6, lane = t & 63;
    if (lane == 0) {
        red[wave][0] = s0r; red[wave][1] = q0;
        red[wave][2] = s1r; red[wave][3] = q1;
        red[wave][4] = s2r; red[wave][5] = q2;
    }
    __syncthreads();
    if (t < 6) {
        float v = red[0][t] + red[1][t] + red[2][t] + red[3][t];
        int ch = t >> 1, which = t & 1;
        atomicAdd(&stats[(b * 3 + ch) * 2 + which], v);
    }
}

// ------------- instance norm + tanh, interleaved, swizzled like conv -----------
// In-place for iters 0..8 (same XCD reads back what conv wrote to its L2);
// last iter scatters back to the planar [B,3,H,W] output.
__global__ __launch_bounds__(256) void norm_kernel(
    const float4* __restrict__ y, float* __restrict__ outp,
    const float* __restrict__ stats,
    const float* __restrict__ gamma, const float* __restrict__ beta,
    int planar)
{
    int p = blockIdx.x;
    int logical = (p & 7) * (NBLK / 8) + (p >> 3);
    int b     = logical & 31;
    int chunk = logical >> 5;
    int pix   = chunk * 256 + threadIdx.x;
    int g     = b * HWS + pix;

    float4 v = y[g];
    float vin[3] = {v.x, v.y, v.z};
    float r[3];
    #pragma unroll
    for (int c = 0; c < 3; ++c) {
        float s  = stats[(b * 3 + c) * 2 + 0];
        float q  = stats[(b * 3 + c) * 2 + 1];
        float mean = s * (1.f / HWS);
        float var  = fmaxf(q * (1.f / HWS) - mean * mean, 0.f);
        float gsc  = gamma[c] * rsqrtf(var + EPS_IN);
        r[c] = fast_tanh((vin[c] - mean) * gsc + beta[c]);
    }
    if (planar) {
        float* ob = outp + (size_t)b * (CC * HWS) + pix;
        ob[0]       = r[0];
        ob[HWS]     = r[1];
        ob[2 * HWS] = r[2];
    } else {
        ((float4*)outp)[g] = make_float4(r[0], r[1], r[2], 0.f);
    }
}

extern "C" void kernel_launch(void* const* d_in, const int* in_sizes, int n_in,
                              void* d_out, int out_size, void* d_ws, size_t ws_size,
                              hipStream_t stream) {
    const float* x     = (const float*)d_in[0];
    const float* wt    = (const float*)d_in[1];
    const float* off   = (const float*)d_in[2];   // batch-tiled -> plane 0
    const float* gamma = (const float*)d_in[3];
    const float* beta  = (const float*)d_in[4];

    float* out  = (float*)d_out;
    float* bufA = (float*)d_ws;                          // NPIX float4 = 25.7 MB
    float* bufB = bufA + (size_t)NPIX * 4;               // NPIX float4 = 25.7 MB
    int4*  ti   = (int4*)(bufB + (size_t)NPIX * 4);      // 7.2 MB
    float4* tw  = (float4*)((char*)ti + (size_t)NTAPS * 16); // 7.2 MB
    float* stats = (float*)((char*)tw + (size_t)NTAPS * 16); // 7.7 KB
    // ws: 2*25.7MB + 2*7.2MB + 7.7KB ~= 66 MB

    zero_kernel<<<(LNUM * 192 + 255) / 256, 256, 0, stream>>>(stats, LNUM * 192);
    taps_kernel<<<NTAPS / 256, 256, 0, stream>>>(off, ti, tw);
    pack_kernel<<<NBLK, 256, 0, stream>>>(x, (float4*)bufB);

    const float4* cur = (const float4*)bufB;
    for (int it = 0; it < LNUM; ++it) {
        float* conv_out = (it & 1) ? bufB : bufA;
        float* st = stats + it * 192;
        conv_kernel<<<NBLK, 256, 0, stream>>>(cur, ti, tw, wt, (float4*)conv_out, st);
        int last = (it == LNUM - 1);
        norm_kernel<<<NBLK, 256, 0, stream>>>((const float4*)conv_out,
                                              last ? out : conv_out,
                                              st, gamma, beta, last);
        cur = (const float4*)conv_out;
    }
}